// Round 8
// baseline (93.916 us; speedup 1.0000x reference)
//
#include <hip/hip_runtime.h>
#include <hip/hip_bf16.h>

#define D_EMB 1024
#define T_LEN 4096
#define NTASK 1088  // attn tasks per batch: sum of ceil((t+1)/8), t=0..127 = 8*136

typedef short short8 __attribute__((ext_vector_type(8)));
typedef float f32x4 __attribute__((ext_vector_type(4)));
typedef float f32x16 __attribute__((ext_vector_type(16)));
typedef float float4v __attribute__((ext_vector_type(4)));

__device__ __forceinline__ unsigned short f32_to_bf16(float f) {
    union { float f; unsigned int u; } c; c.f = f;
    unsigned int u = c.u;
    return (unsigned short)((u + 0x7FFFu + ((u >> 16) & 1u)) >> 16);
}
__device__ __forceinline__ float bf16_to_f32(unsigned short v) {
    union { unsigned int u; float f; } c; c.u = ((unsigned int)v) << 16;
    return c.f;
}
__device__ __forceinline__ unsigned cvtpk_bf16(float a, float b) {
    unsigned r;
    asm("v_cvt_pk_bf16_f32 %0, %1, %2" : "=v"(r) : "v"(a), "v"(b));
    return r;
}
__device__ __forceinline__ void gl_lds16(const void* g, void* l) {
    __builtin_amdgcn_global_load_lds(
        (const __attribute__((address_space(1))) unsigned int*)(g),
        (__attribute__((address_space(3))) unsigned int*)(l), 16, 0, 0);
}

// scale folded into Q: 1/sqrt(64) * log2(e)  (softmax done in exp2 domain)
#define QSCALE (0.125f * 1.44269504f)

// ---------------- kernel 0: convert W -> bf16, XOR-swizzled within 64-col blocks
__global__ __launch_bounds__(256) void convert_w(const float* __restrict__ Wk,
                                                 const float* __restrict__ Wq,
                                                 const float* __restrict__ Wv,
                                                 unsigned short* __restrict__ Wb) {
    int e = (blockIdx.x * 256 + threadIdx.x) * 8;
    const float* src;
    if (e < 65536) src = Wk + e;
    else if (e < 131072) src = Wq + (e - 65536);
    else src = Wv + (e - 131072);
    float4v a0 = *(const float4v*)src;
    float4v a1 = *(const float4v*)(src + 4);
    short8 r;
    r[0] = (short)f32_to_bf16(a0[0]); r[1] = (short)f32_to_bf16(a0[1]);
    r[2] = (short)f32_to_bf16(a0[2]); r[3] = (short)f32_to_bf16(a0[3]);
    r[4] = (short)f32_to_bf16(a1[0]); r[5] = (short)f32_to_bf16(a1[1]);
    r[6] = (short)f32_to_bf16(a1[2]); r[7] = (short)f32_to_bf16(a1[3]);
    int row = e >> 10;
    int dst = e ^ ((row & 7) << 3);
    *(short8*)(Wb + dst) = r;
}

// ---------------- kernel 1: QKV projection, LDS-staged GEMM + depth-2 x prefetch
__global__ __launch_bounds__(256, 2) void qkv_proj(const float* __restrict__ x,
                                                   const unsigned short* __restrict__ Wb,
                                                   unsigned short* __restrict__ Kb,
                                                   unsigned short* __restrict__ Qb,
                                                   unsigned short* __restrict__ Vt) {
    __shared__ __attribute__((aligned(16))) unsigned short Wsl[2][12288];  // [192][64] bf16

    int tid = threadIdx.x;
    int lane = tid & 63, wave = tid >> 6;
    int lo = lane & 15, hi = lane >> 4;
    int rg = wave >> 1, nh = wave & 1;
    int row0 = blockIdx.x * 32;

    const float* xp = x + (size_t)(row0 + rg * 16 + lo) * D_EMB + hi * 8;

    f32x4 acc[6];
#pragma unroll
    for (int i = 0; i < 6; i++) acc[i] = (f32x4){0.f, 0.f, 0.f, 0.f};

    // x prefetch depth 2: xa = kt, xb = kt+1
    float4v xa0 = *(const float4v*)(xp);
    float4v xa1 = *(const float4v*)(xp + 4);
    float4v xa2 = *(const float4v*)(xp + 32);
    float4v xa3 = *(const float4v*)(xp + 36);
    float4v xb0 = *(const float4v*)(xp + 64);
    float4v xb1 = *(const float4v*)(xp + 68);
    float4v xb2 = *(const float4v*)(xp + 96);
    float4v xb3 = *(const float4v*)(xp + 100);

    // stage W slice 0
#pragma unroll
    for (int j = 0; j < 6; j++) {
        int unit = j * 4 + wave;
        int u = unit * 64 + lane;
        gl_lds16(Wb + (size_t)(u >> 3) * D_EMB + (u & 7) * 8, &Wsl[0][unit * 512]);
    }
    __syncthreads();

    int buf = 0;
    int xorm = (lo & 7) << 4;
    int rowbase = nh * 96 + lo;

    for (int kt = 0; kt < 16; kt++) {
        // issue x loads for kt+2 (clamped)
        int ktn = (kt < 14) ? kt + 2 : 15;
        const float* pn = xp + ktn * 64;
        float4v xc0 = *(const float4v*)(pn);
        float4v xc1 = *(const float4v*)(pn + 4);
        float4v xc2 = *(const float4v*)(pn + 32);
        float4v xc3 = *(const float4v*)(pn + 36);

        // stage W slice kt+1
        if (kt < 15) {
            int k0n = (kt + 1) * 64;
#pragma unroll
            for (int j = 0; j < 6; j++) {
                int unit = j * 4 + wave;
                int u = unit * 64 + lane;
                gl_lds16(Wb + (size_t)(u >> 3) * D_EMB + k0n + (u & 7) * 8,
                         &Wsl[buf ^ 1][unit * 512]);
            }
        }

        // cvt current x -> A fragments
        short8 af[2];
        {
            union { unsigned u[4]; short8 s; } c;
            c.u[0] = cvtpk_bf16(xa0[0], xa0[1]);
            c.u[1] = cvtpk_bf16(xa0[2], xa0[3]);
            c.u[2] = cvtpk_bf16(xa1[0], xa1[1]);
            c.u[3] = cvtpk_bf16(xa1[2], xa1[3]);
            af[0] = c.s;
            c.u[0] = cvtpk_bf16(xa2[0], xa2[1]);
            c.u[1] = cvtpk_bf16(xa2[2], xa2[3]);
            c.u[2] = cvtpk_bf16(xa3[0], xa3[1]);
            c.u[3] = cvtpk_bf16(xa3[2], xa3[3]);
            af[1] = c.s;
        }

        const char* sb = (const char*)&Wsl[buf][0];
#pragma unroll
        for (int i = 0; i < 6; i++) {
            int row = rowbase + i * 16;
#pragma unroll
            for (int ks = 0; ks < 2; ks++) {
                short8 bfrag = *(const short8*)(sb + row * 128 + ((ks * 64 + hi * 16) ^ xorm));
                acc[i] = __builtin_amdgcn_mfma_f32_16x16x32_bf16(af[ks], bfrag, acc[i], 0, 0, 0);
            }
        }
        __syncthreads();
        buf ^= 1;
        xa0 = xb0; xa1 = xb1; xa2 = xb2; xa3 = xb3;
        xb0 = xc0; xb1 = xc1; xb2 = xc2; xb3 = xc3;
    }

    // epilogue
#pragma unroll
    for (int i = 0; i < 6; i++) {
        int n = nh * 6 + i;
#pragma unroll
        for (int r = 0; r < 4; r++) {
            int grow = row0 + rg * 16 + hi * 4 + r;
            float val = acc[i][r];
            if (n < 4) {
                Kb[(size_t)grow * 64 + n * 16 + lo] = f32_to_bf16(val);
            } else if (n < 8) {
                Qb[(size_t)grow * 64 + (n - 4) * 16 + lo] = f32_to_bf16(val * QSCALE);
            } else {
                int bb = grow >> 12;
                Vt[((size_t)bb * 64 + (n - 8) * 16 + lo) * T_LEN + (grow & 4095)] = f32_to_bf16(val);
            }
        }
    }
}

// ---------------- kernel 2: causal flash attention, 1 wave per task.
// Task = (32-row q tile, chunk of <=256 keys = 8 32-key units). Cross-iteration
// software pipeline: QKT(u+1) issued from K regs loaded one iter earlier, so
// softmax(u) VALU overlaps QKT(u+1) MFMA; K(u+2)/V(u+1) issued mid-iteration.
__global__ __launch_bounds__(64, 3) void attn(const unsigned short* __restrict__ Qb,
                                              const unsigned short* __restrict__ Kb,
                                              const unsigned short* __restrict__ Vt,
                                              unsigned short* __restrict__ Opart,
                                              float* __restrict__ Mpart,
                                              float* __restrict__ Lpart) {
    int lane = threadIdx.x;
    int q32 = lane & 31;
    int hi = lane >> 5;
    int s = blockIdx.x;   // 0..1087, heavy tiles first
    int b = blockIdx.y;

    // decode (tile t, chunk c): group k has tiles [8k,8k+7], k+1 chunks each
    int k = 15, rem = s;
    while (rem >= 8 * (k + 1)) { rem -= 8 * (k + 1); k--; }
    int cpt = k + 1;
    int ti = rem / cpt;
    int t = (k << 3) + 7 - ti;
    int c = rem - ti * cpt;

    int u0 = c * 8;
    int u1 = min(u0 + 8, t + 1);   // 32-key units

    size_t base = (size_t)b * T_LEN;
    int qg = t * 32 + q32;

    // Q B-fragments
    short8 qf[4];
    const unsigned short* qp = Qb + (base + qg) * 64 + hi * 8;
#pragma unroll
    for (int d = 0; d < 4; d++) qf[d] = *(const short8*)(qp + d * 16);

    size_t vbase = ((size_t)b * 64 + q32) * T_LEN;
    f32x16 o0 = {0.f}, o1 = {0.f};
    float m = -3e38f, l = 0.f;

    // prologue: K(u0) -> QKT -> scC; V(u0) -> vA; K(u0+1 clamped) -> kB
    short8 kB0, kB1, kB2, kB3, vA0, vA1, vA2, vA3;
    {
        const unsigned short* kp = Kb + (base + u0 * 32 + q32) * 64 + hi * 8;
        kB0 = *(const short8*)kp;
        kB1 = *(const short8*)(kp + 16);
        kB2 = *(const short8*)(kp + 32);
        kB3 = *(const short8*)(kp + 48);
    }
    f32x16 scC = {0.f};
    scC = __builtin_amdgcn_mfma_f32_32x32x16_bf16(kB0, qf[0], scC, 0, 0, 0);
    scC = __builtin_amdgcn_mfma_f32_32x32x16_bf16(kB1, qf[1], scC, 0, 0, 0);
    scC = __builtin_amdgcn_mfma_f32_32x32x16_bf16(kB2, qf[2], scC, 0, 0, 0);
    scC = __builtin_amdgcn_mfma_f32_32x32x16_bf16(kB3, qf[3], scC, 0, 0, 0);
    {
        const unsigned short* vp = Vt + vbase + u0 * 32 + hi * 8;
        vA0 = *(const short8*)vp;
        vA1 = *(const short8*)(vp + 16);
        vA2 = *(const short8*)(vp + 32 * T_LEN);
        vA3 = *(const short8*)(vp + 32 * T_LEN + 16);
        int un = (u0 + 1 < u1) ? u0 + 1 : u0;
        const unsigned short* kp = Kb + (base + un * 32 + q32) * 64 + hi * 8;
        kB0 = *(const short8*)kp;
        kB1 = *(const short8*)(kp + 16);
        kB2 = *(const short8*)(kp + 32);
        kB3 = *(const short8*)(kp + 48);
    }

    for (int u = u0; u < u1; ++u) {
        bool hn = (u + 1 < u1);
        // QKT for u+1 — MFMA overlaps the softmax VALU below
        f32x16 scN = {0.f};
        if (hn) {
            scN = __builtin_amdgcn_mfma_f32_32x32x16_bf16(kB0, qf[0], scN, 0, 0, 0);
            scN = __builtin_amdgcn_mfma_f32_32x32x16_bf16(kB1, qf[1], scN, 0, 0, 0);
            scN = __builtin_amdgcn_mfma_f32_32x32x16_bf16(kB2, qf[2], scN, 0, 0, 0);
            scN = __builtin_amdgcn_mfma_f32_32x32x16_bf16(kB3, qf[3], scN, 0, 0, 0);
            // issue K(u+2) now; consumed at next iteration's top
            int unn = (u + 2 < u1) ? u + 2 : u + 1;
            const unsigned short* kp = Kb + (base + unn * 32 + q32) * 64 + hi * 8;
            kB0 = *(const short8*)kp;
            kB1 = *(const short8*)(kp + 16);
            kB2 = *(const short8*)(kp + 32);
            kB3 = *(const short8*)(kp + 48);
        }

        if (u == t) {  // diagonal unit: causal mask
#pragma unroll
            for (int r = 0; r < 16; ++r) {
                int ko = (r & 3) + 8 * (r >> 2) + 4 * hi;
                scC[r] = (ko <= q32) ? scC[r] : -3e38f;
            }
        }

        // row max: tree over 16 regs + one cross-half exchange
        float x0 = fmaxf(scC[0], scC[8]),  x1 = fmaxf(scC[1], scC[9]);
        float x2 = fmaxf(scC[2], scC[10]), x3 = fmaxf(scC[3], scC[11]);
        float x4 = fmaxf(scC[4], scC[12]), x5 = fmaxf(scC[5], scC[13]);
        float x6 = fmaxf(scC[6], scC[14]), x7 = fmaxf(scC[7], scC[15]);
        x0 = fmaxf(x0, x4); x1 = fmaxf(x1, x5); x2 = fmaxf(x2, x6); x3 = fmaxf(x3, x7);
        x0 = fmaxf(x0, x2); x1 = fmaxf(x1, x3);
        float mx = fmaxf(x0, x1);
        mx = fmaxf(mx, __shfl_xor(mx, 32));

        // defer-max (THR=8)
        if (__any(mx > m + 8.0f)) {
            float mn = fmaxf(m, mx);
            float al = exp2f(m - mn);
            m = mn; l *= al;
#pragma unroll
            for (int r = 0; r < 16; ++r) { o0[r] *= al; o1[r] *= al; }
        }

#pragma unroll
        for (int r = 0; r < 16; ++r) scC[r] = exp2f(scC[r] - m);
        float y0 = (scC[0] + scC[8]) + (scC[4] + scC[12]);
        float y1 = (scC[1] + scC[9]) + (scC[5] + scC[13]);
        float y2 = (scC[2] + scC[10]) + (scC[6] + scC[14]);
        float y3 = (scC[3] + scC[11]) + (scC[7] + scC[15]);
        float sum = (y0 + y1) + (y2 + y3);
        sum += __shfl_xor(sum, 32);
        l += sum;

        // pack P -> bf16 PV B-fragments (cvt_pk + permlane32_swap)
        unsigned bb0, bb1, bb2, bb3, bb4, bb5, bb6, bb7;
        bb0 = cvtpk_bf16(scC[0],  scC[1]);
        bb1 = cvtpk_bf16(scC[2],  scC[3]);
        bb2 = cvtpk_bf16(scC[4],  scC[5]);
        bb3 = cvtpk_bf16(scC[6],  scC[7]);
        bb4 = cvtpk_bf16(scC[8],  scC[9]);
        bb5 = cvtpk_bf16(scC[10], scC[11]);
        bb6 = cvtpk_bf16(scC[12], scC[13]);
        bb7 = cvtpk_bf16(scC[14], scC[15]);
        asm("v_permlane32_swap_b32 %0, %1" : "+v"(bb0), "+v"(bb2));
        asm("v_permlane32_swap_b32 %0, %1" : "+v"(bb1), "+v"(bb3));
        asm("v_permlane32_swap_b32 %0, %1" : "+v"(bb4), "+v"(bb6));
        asm("v_permlane32_swap_b32 %0, %1" : "+v"(bb5), "+v"(bb7));
        union U8 { unsigned u[4]; short8 s; };
        U8 p0; p0.u[0] = bb0; p0.u[1] = bb1; p0.u[2] = bb2; p0.u[3] = bb3;
        U8 p1; p1.u[0] = bb4; p1.u[1] = bb5; p1.u[2] = bb6; p1.u[3] = bb7;

        // O^T += V^T * P^T
        o0 = __builtin_amdgcn_mfma_f32_32x32x16_bf16(vA0, p0.s, o0, 0, 0, 0);
        o0 = __builtin_amdgcn_mfma_f32_32x32x16_bf16(vA1, p1.s, o0, 0, 0, 0);
        o1 = __builtin_amdgcn_mfma_f32_32x32x16_bf16(vA2, p0.s, o1, 0, 0, 0);
        o1 = __builtin_amdgcn_mfma_f32_32x32x16_bf16(vA3, p1.s, o1, 0, 0, 0);

        // issue V(u+1); consumed at next iteration's PV
        if (hn) {
            const unsigned short* vp = Vt + vbase + (u + 1) * 32 + hi * 8;
            vA0 = *(const short8*)vp;
            vA1 = *(const short8*)(vp + 16);
            vA2 = *(const short8*)(vp + 32 * T_LEN);
            vA3 = *(const short8*)(vp + 32 * T_LEN + 16);
        }
        scC = scN;
    }

    // store partial: Opart[(b*NTASK+s)][q32][h] bf16
    size_t tbase = ((size_t)(b * NTASK + s) * 32 + q32) * 64;
#pragma unroll
    for (int hb = 0; hb < 2; hb++) {
#pragma unroll
        for (int g = 0; g < 4; g++) {
            float e0 = hb ? o1[4 * g] : o0[4 * g];
            float e1 = hb ? o1[4 * g + 1] : o0[4 * g + 1];
            float e2 = hb ? o1[4 * g + 2] : o0[4 * g + 2];
            float e3 = hb ? o1[4 * g + 3] : o0[4 * g + 3];
            unsigned w0 = cvtpk_bf16(e0, e1);
            unsigned w1 = cvtpk_bf16(e2, e3);
            int h0 = hb * 32 + g * 8 + hi * 4;
            *reinterpret_cast<uint2*>(Opart + tbase + h0) = make_uint2(w0, w1);
        }
    }
    if (lane < 32) {
        Mpart[(b * NTASK + s) * 32 + q32] = m;
        Lpart[(b * NTASK + s) * 32 + q32] = l;
    }
}

// ---------------- kernel 3: merge per-chunk partials, divide by l
__global__ __launch_bounds__(256) void attn_merge(const unsigned short* __restrict__ Opart,
                                                  const float* __restrict__ Mpart,
                                                  const float* __restrict__ Lpart,
                                                  float* __restrict__ out) {
    int tid = threadIdx.x;
    int g = blockIdx.x * 64 + (tid >> 2);   // global row
    int h0 = (tid & 3) * 16;
    int b = g >> 12, t = g & 4095;
    int tile = t >> 5, r32 = t & 31;
    int k = tile >> 3;
    int nch = k + 1;
    int s0 = 8 * (136 - (((k + 1) * (k + 2)) >> 1)) + (7 - (tile & 7)) * nch;
    int tb = b * NTASK + s0;

    float mm = -3e38f;
    for (int i = 0; i < nch; i++) mm = fmaxf(mm, Mpart[(tb + i) * 32 + r32]);
    float ll = 0.f;
    float acc[16];
#pragma unroll
    for (int e = 0; e < 16; e++) acc[e] = 0.f;
    for (int i = 0; i < nch; i++) {
        float a = exp2f(Mpart[(tb + i) * 32 + r32] - mm);
        ll += a * Lpart[(tb + i) * 32 + r32];
        const unsigned short* op = Opart + ((size_t)(tb + i) * 32 + r32) * 64 + h0;
        short8 v0 = *(const short8*)op;
        short8 v1 = *(const short8*)(op + 8);
#pragma unroll
        for (int e = 0; e < 8; e++) {
            acc[e]     += a * bf16_to_f32((unsigned short)v0[e]);
            acc[8 + e] += a * bf16_to_f32((unsigned short)v1[e]);
        }
    }
    float inv = 1.f / ll;
    float* dst = out + (size_t)g * 64 + h0;
#pragma unroll
    for (int e = 0; e < 16; e++) dst[e] = acc[e] * inv;
}

extern "C" void kernel_launch(void* const* d_in, const int* in_sizes, int n_in,
                              void* d_out, int out_size, void* d_ws, size_t ws_size,
                              hipStream_t stream) {
    (void)in_sizes; (void)n_in; (void)out_size; (void)ws_size;
    const float* x  = (const float*)d_in[0];
    const float* Wk = (const float*)d_in[1];
    const float* Wq = (const float*)d_in[2];
    const float* Wv = (const float*)d_in[3];
    float* out = (float*)d_out;

    unsigned short* Wb = (unsigned short*)d_ws;              // 192*1024 (swizzled)
    unsigned short* Kb = Wb + 196608;                        // 16384*64
    unsigned short* Qb = Kb + 1048576;                       // pre-scaled by QSCALE
    unsigned short* Vt = Qb + 1048576;                       // (b, 64, t)
    unsigned short* Opart = Vt + 1048576;                    // [4*1088][32][64] bf16
    float* Mpart = (float*)(Opart + (size_t)4 * NTASK * 32 * 64);
    float* Lpart = Mpart + 4 * NTASK * 32;

    hipLaunchKernelGGL(convert_w, dim3(96), dim3(256), 0, stream, Wk, Wq, Wv, Wb);
    hipLaunchKernelGGL(qkv_proj, dim3(512), dim3(256), 0, stream, x, Wb, Kb, Qb, Vt);
    hipLaunchKernelGGL(attn, dim3(NTASK, 4), dim3(64), 0, stream, Qb, Kb, Vt, Opart, Mpart, Lpart);
    hipLaunchKernelGGL(attn_merge, dim3(256), dim3(256), 0, stream, Opart, Mpart, Lpart, out);
}

// Round 9
// 93.138 us; speedup vs baseline: 1.0084x; 1.0084x over previous
//
#include <hip/hip_runtime.h>
#include <hip/hip_bf16.h>

#define D_EMB 1024
#define T_LEN 4096
#define NTASK 1088  // attn tasks per batch: sum of ceil((t+1)/8), t=0..127 = 8*136

typedef short short8 __attribute__((ext_vector_type(8)));
typedef float f32x4 __attribute__((ext_vector_type(4)));
typedef float f32x16 __attribute__((ext_vector_type(16)));
typedef float float4v __attribute__((ext_vector_type(4)));

__device__ __forceinline__ unsigned short f32_to_bf16(float f) {
    union { float f; unsigned int u; } c; c.f = f;
    unsigned int u = c.u;
    return (unsigned short)((u + 0x7FFFu + ((u >> 16) & 1u)) >> 16);
}
__device__ __forceinline__ float bf16_to_f32(unsigned short v) {
    union { unsigned int u; float f; } c; c.u = ((unsigned int)v) << 16;
    return c.f;
}
__device__ __forceinline__ unsigned cvtpk_bf16(float a, float b) {
    unsigned r;
    asm("v_cvt_pk_bf16_f32 %0, %1, %2" : "=v"(r) : "v"(a), "v"(b));
    return r;
}
__device__ __forceinline__ void gl_lds16(const void* g, void* l) {
    __builtin_amdgcn_global_load_lds(
        (const __attribute__((address_space(1))) unsigned int*)(g),
        (__attribute__((address_space(3))) unsigned int*)(l), 16, 0, 0);
}

// scale folded into Q: 1/sqrt(64) * log2(e)  (softmax done in exp2 domain)
#define QSCALE (0.125f * 1.44269504f)

// ---------------- kernel 0: convert W -> bf16, XOR-swizzled within 64-col blocks
__global__ __launch_bounds__(256) void convert_w(const float* __restrict__ Wk,
                                                 const float* __restrict__ Wq,
                                                 const float* __restrict__ Wv,
                                                 unsigned short* __restrict__ Wb) {
    int e = (blockIdx.x * 256 + threadIdx.x) * 8;
    const float* src;
    if (e < 65536) src = Wk + e;
    else if (e < 131072) src = Wq + (e - 65536);
    else src = Wv + (e - 131072);
    float4v a0 = *(const float4v*)src;
    float4v a1 = *(const float4v*)(src + 4);
    short8 r;
    r[0] = (short)f32_to_bf16(a0[0]); r[1] = (short)f32_to_bf16(a0[1]);
    r[2] = (short)f32_to_bf16(a0[2]); r[3] = (short)f32_to_bf16(a0[3]);
    r[4] = (short)f32_to_bf16(a1[0]); r[5] = (short)f32_to_bf16(a1[1]);
    r[6] = (short)f32_to_bf16(a1[2]); r[7] = (short)f32_to_bf16(a1[3]);
    int row = e >> 10;
    int dst = e ^ ((row & 7) << 3);
    *(short8*)(Wb + dst) = r;
}

// ---------------- kernel 1: QKV projection, LDS-staged GEMM + depth-2 x prefetch
__global__ __launch_bounds__(256, 2) void qkv_proj(const float* __restrict__ x,
                                                   const unsigned short* __restrict__ Wb,
                                                   unsigned short* __restrict__ Kb,
                                                   unsigned short* __restrict__ Qb,
                                                   unsigned short* __restrict__ Vt) {
    __shared__ __attribute__((aligned(16))) unsigned short Wsl[2][12288];  // [192][64] bf16

    int tid = threadIdx.x;
    int lane = tid & 63, wave = tid >> 6;
    int lo = lane & 15, hi = lane >> 4;
    int rg = wave >> 1, nh = wave & 1;
    int row0 = blockIdx.x * 32;

    const float* xp = x + (size_t)(row0 + rg * 16 + lo) * D_EMB + hi * 8;

    f32x4 acc[6];
#pragma unroll
    for (int i = 0; i < 6; i++) acc[i] = (f32x4){0.f, 0.f, 0.f, 0.f};

    // x prefetch depth 2: xa = kt, xb = kt+1
    float4v xa0 = *(const float4v*)(xp);
    float4v xa1 = *(const float4v*)(xp + 4);
    float4v xa2 = *(const float4v*)(xp + 32);
    float4v xa3 = *(const float4v*)(xp + 36);
    float4v xb0 = *(const float4v*)(xp + 64);
    float4v xb1 = *(const float4v*)(xp + 68);
    float4v xb2 = *(const float4v*)(xp + 96);
    float4v xb3 = *(const float4v*)(xp + 100);

    // stage W slice 0
#pragma unroll
    for (int j = 0; j < 6; j++) {
        int unit = j * 4 + wave;
        int u = unit * 64 + lane;
        gl_lds16(Wb + (size_t)(u >> 3) * D_EMB + (u & 7) * 8, &Wsl[0][unit * 512]);
    }
    __syncthreads();

    int buf = 0;
    int xorm = (lo & 7) << 4;
    int rowbase = nh * 96 + lo;

    for (int kt = 0; kt < 16; kt++) {
        // issue x loads for kt+2 (clamped)
        int ktn = (kt < 14) ? kt + 2 : 15;
        const float* pn = xp + ktn * 64;
        float4v xc0 = *(const float4v*)(pn);
        float4v xc1 = *(const float4v*)(pn + 4);
        float4v xc2 = *(const float4v*)(pn + 32);
        float4v xc3 = *(const float4v*)(pn + 36);

        // stage W slice kt+1
        if (kt < 15) {
            int k0n = (kt + 1) * 64;
#pragma unroll
            for (int j = 0; j < 6; j++) {
                int unit = j * 4 + wave;
                int u = unit * 64 + lane;
                gl_lds16(Wb + (size_t)(u >> 3) * D_EMB + k0n + (u & 7) * 8,
                         &Wsl[buf ^ 1][unit * 512]);
            }
        }

        // cvt current x -> A fragments
        short8 af[2];
        {
            union { unsigned u[4]; short8 s; } c;
            c.u[0] = cvtpk_bf16(xa0[0], xa0[1]);
            c.u[1] = cvtpk_bf16(xa0[2], xa0[3]);
            c.u[2] = cvtpk_bf16(xa1[0], xa1[1]);
            c.u[3] = cvtpk_bf16(xa1[2], xa1[3]);
            af[0] = c.s;
            c.u[0] = cvtpk_bf16(xa2[0], xa2[1]);
            c.u[1] = cvtpk_bf16(xa2[2], xa2[3]);
            c.u[2] = cvtpk_bf16(xa3[0], xa3[1]);
            c.u[3] = cvtpk_bf16(xa3[2], xa3[3]);
            af[1] = c.s;
        }

        const char* sb = (const char*)&Wsl[buf][0];
#pragma unroll
        for (int i = 0; i < 6; i++) {
            int row = rowbase + i * 16;
#pragma unroll
            for (int ks = 0; ks < 2; ks++) {
                short8 bfrag = *(const short8*)(sb + row * 128 + ((ks * 64 + hi * 16) ^ xorm));
                acc[i] = __builtin_amdgcn_mfma_f32_16x16x32_bf16(af[ks], bfrag, acc[i], 0, 0, 0);
            }
        }
        __syncthreads();
        buf ^= 1;
        xa0 = xb0; xa1 = xb1; xa2 = xb2; xa3 = xb3;
        xb0 = xc0; xb1 = xc1; xb2 = xc2; xb3 = xc3;
    }

    // epilogue
#pragma unroll
    for (int i = 0; i < 6; i++) {
        int n = nh * 6 + i;
#pragma unroll
        for (int r = 0; r < 4; r++) {
            int grow = row0 + rg * 16 + hi * 4 + r;
            float val = acc[i][r];
            if (n < 4) {
                Kb[(size_t)grow * 64 + n * 16 + lo] = f32_to_bf16(val);
            } else if (n < 8) {
                Qb[(size_t)grow * 64 + (n - 4) * 16 + lo] = f32_to_bf16(val * QSCALE);
            } else {
                int bb = grow >> 12;
                Vt[((size_t)bb * 64 + (n - 8) * 16 + lo) * T_LEN + (grow & 4095)] = f32_to_bf16(val);
            }
        }
    }
}

// ---------------- kernel 2: causal flash attention, 1 wave per task.
// Task = (32-row q tile, chunk of <=256 keys). 1D grid with XCD batch-affinity
// swizzle: lin = (s>>1)*8 + (s&1)*4 + b  ->  XCD (lin%8) = b + 4*(s&1), so each
// XCD touches exactly one batch's K/V (~1MB, L2-resident). Straight-line body;
// latency hidden by 4 waves/SIMD TLP (launch_bounds (64,4)).
__global__ __launch_bounds__(64, 4) void attn(const unsigned short* __restrict__ Qb,
                                              const unsigned short* __restrict__ Kb,
                                              const unsigned short* __restrict__ Vt,
                                              unsigned short* __restrict__ Opart,
                                              float* __restrict__ Mpart,
                                              float* __restrict__ Lpart) {
    int lane = threadIdx.x;
    int q32 = lane & 31;
    int hi = lane >> 5;
    unsigned lin = blockIdx.x;
    int b = lin & 3;
    int s = (int)(((lin >> 3) << 1) | ((lin >> 2) & 1));  // 0..1087, heavy first

    // decode (tile t, chunk c): group k has tiles [8k,8k+7], k+1 chunks each
    int k = 15, rem = s;
    while (rem >= 8 * (k + 1)) { rem -= 8 * (k + 1); k--; }
    int cpt = k + 1;
    int ti = rem / cpt;
    int t = (k << 3) + 7 - ti;
    int c = rem - ti * cpt;

    int u0 = c * 8;
    int u1 = min(u0 + 8, t + 1);   // 32-key units

    size_t base = (size_t)b * T_LEN;
    int qg = t * 32 + q32;

    // Q B-fragments
    short8 qf[4];
    const unsigned short* qp = Qb + (base + qg) * 64 + hi * 8;
#pragma unroll
    for (int d = 0; d < 4; d++) qf[d] = *(const short8*)(qp + d * 16);

    size_t vbase = ((size_t)b * 64 + q32) * T_LEN;
    f32x16 o0 = {0.f}, o1 = {0.f};
    float m = -3e38f, l = 0.f;

    for (int u = u0; u < u1; ++u) {
        const unsigned short* kp = Kb + (base + u * 32 + q32) * 64 + hi * 8;
        short8 kc0 = *(const short8*)kp;
        short8 kc1 = *(const short8*)(kp + 16);
        short8 kc2 = *(const short8*)(kp + 32);
        short8 kc3 = *(const short8*)(kp + 48);
        const unsigned short* vp = Vt + vbase + u * 32 + hi * 8;
        short8 vc0 = *(const short8*)vp;
        short8 vc1 = *(const short8*)(vp + 16);
        short8 vc2 = *(const short8*)(vp + 32 * T_LEN);
        short8 vc3 = *(const short8*)(vp + 32 * T_LEN + 16);

        // S^T = K * Q^T : col = q (lane&31), row k = (r&3)+8*(r>>2)+4*hi
        f32x16 sc = {0.f};
        sc = __builtin_amdgcn_mfma_f32_32x32x16_bf16(kc0, qf[0], sc, 0, 0, 0);
        sc = __builtin_amdgcn_mfma_f32_32x32x16_bf16(kc1, qf[1], sc, 0, 0, 0);
        sc = __builtin_amdgcn_mfma_f32_32x32x16_bf16(kc2, qf[2], sc, 0, 0, 0);
        sc = __builtin_amdgcn_mfma_f32_32x32x16_bf16(kc3, qf[3], sc, 0, 0, 0);

        if (u == t) {  // diagonal unit: causal mask
#pragma unroll
            for (int r = 0; r < 16; ++r) {
                int ko = (r & 3) + 8 * (r >> 2) + 4 * hi;
                sc[r] = (ko <= q32) ? sc[r] : -3e38f;
            }
        }

        // row max: max3-shaped tree (fused to v_max3_f32) + one cross-half shfl
        float t0 = fmaxf(fmaxf(sc[0], sc[1]), sc[2]);
        float t1 = fmaxf(fmaxf(sc[3], sc[4]), sc[5]);
        float t2 = fmaxf(fmaxf(sc[6], sc[7]), sc[8]);
        float t3 = fmaxf(fmaxf(sc[9], sc[10]), sc[11]);
        float t4 = fmaxf(fmaxf(sc[12], sc[13]), sc[14]);
        float t5 = fmaxf(fmaxf(t0, t1), sc[15]);
        float t6 = fmaxf(fmaxf(t2, t3), t4);
        float mx = fmaxf(t5, t6);
        mx = fmaxf(mx, __shfl_xor(mx, 32));

        // defer-max (THR=8)
        if (__any(mx > m + 8.0f)) {
            float mn = fmaxf(m, mx);
            float al = exp2f(m - mn);
            m = mn; l *= al;
#pragma unroll
            for (int r = 0; r < 16; ++r) { o0[r] *= al; o1[r] *= al; }
        }

#pragma unroll
        for (int r = 0; r < 16; ++r) sc[r] = exp2f(sc[r] - m);
        float y0 = (sc[0] + sc[8]) + (sc[4] + sc[12]);
        float y1 = (sc[1] + sc[9]) + (sc[5] + sc[13]);
        float y2 = (sc[2] + sc[10]) + (sc[6] + sc[14]);
        float y3 = (sc[3] + sc[11]) + (sc[7] + sc[15]);
        float sum = (y0 + y1) + (y2 + y3);
        sum += __shfl_xor(sum, 32);
        l += sum;

        // pack P -> bf16 PV B-fragments (cvt_pk + permlane32_swap)
        unsigned bb0, bb1, bb2, bb3, bb4, bb5, bb6, bb7;
        bb0 = cvtpk_bf16(sc[0],  sc[1]);
        bb1 = cvtpk_bf16(sc[2],  sc[3]);
        bb2 = cvtpk_bf16(sc[4],  sc[5]);
        bb3 = cvtpk_bf16(sc[6],  sc[7]);
        bb4 = cvtpk_bf16(sc[8],  sc[9]);
        bb5 = cvtpk_bf16(sc[10], sc[11]);
        bb6 = cvtpk_bf16(sc[12], sc[13]);
        bb7 = cvtpk_bf16(sc[14], sc[15]);
        asm("v_permlane32_swap_b32 %0, %1" : "+v"(bb0), "+v"(bb2));
        asm("v_permlane32_swap_b32 %0, %1" : "+v"(bb1), "+v"(bb3));
        asm("v_permlane32_swap_b32 %0, %1" : "+v"(bb4), "+v"(bb6));
        asm("v_permlane32_swap_b32 %0, %1" : "+v"(bb5), "+v"(bb7));
        union U8 { unsigned u[4]; short8 s; };
        U8 p0; p0.u[0] = bb0; p0.u[1] = bb1; p0.u[2] = bb2; p0.u[3] = bb3;
        U8 p1; p1.u[0] = bb4; p1.u[1] = bb5; p1.u[2] = bb6; p1.u[3] = bb7;

        // O^T += V^T * P^T
        o0 = __builtin_amdgcn_mfma_f32_32x32x16_bf16(vc0, p0.s, o0, 0, 0, 0);
        o0 = __builtin_amdgcn_mfma_f32_32x32x16_bf16(vc1, p1.s, o0, 0, 0, 0);
        o1 = __builtin_amdgcn_mfma_f32_32x32x16_bf16(vc2, p0.s, o1, 0, 0, 0);
        o1 = __builtin_amdgcn_mfma_f32_32x32x16_bf16(vc3, p1.s, o1, 0, 0, 0);
    }

    // store partial: Opart[(b*NTASK+s)][q32][h] bf16
    size_t tbase = ((size_t)(b * NTASK + s) * 32 + q32) * 64;
#pragma unroll
    for (int hb = 0; hb < 2; hb++) {
#pragma unroll
        for (int g = 0; g < 4; g++) {
            float e0 = hb ? o1[4 * g] : o0[4 * g];
            float e1 = hb ? o1[4 * g + 1] : o0[4 * g + 1];
            float e2 = hb ? o1[4 * g + 2] : o0[4 * g + 2];
            float e3 = hb ? o1[4 * g + 3] : o0[4 * g + 3];
            unsigned w0 = cvtpk_bf16(e0, e1);
            unsigned w1 = cvtpk_bf16(e2, e3);
            int h0 = hb * 32 + g * 8 + hi * 4;
            *reinterpret_cast<uint2*>(Opart + tbase + h0) = make_uint2(w0, w1);
        }
    }
    if (lane < 32) {
        Mpart[(b * NTASK + s) * 32 + q32] = m;
        Lpart[(b * NTASK + s) * 32 + q32] = l;
    }
}

// ---------------- kernel 3: merge per-chunk partials, divide by l
__global__ __launch_bounds__(256) void attn_merge(const unsigned short* __restrict__ Opart,
                                                  const float* __restrict__ Mpart,
                                                  const float* __restrict__ Lpart,
                                                  float* __restrict__ out) {
    int tid = threadIdx.x;
    int g = blockIdx.x * 64 + (tid >> 2);   // global row
    int h0 = (tid & 3) * 16;
    int b = g >> 12, t = g & 4095;
    int tile = t >> 5, r32 = t & 31;
    int k = tile >> 3;
    int nch = k + 1;
    int s0 = 8 * (136 - (((k + 1) * (k + 2)) >> 1)) + (7 - (tile & 7)) * nch;
    int tb = b * NTASK + s0;

    float mm = -3e38f;
    for (int i = 0; i < nch; i++) mm = fmaxf(mm, Mpart[(tb + i) * 32 + r32]);
    float ll = 0.f;
    float acc[16];
#pragma unroll
    for (int e = 0; e < 16; e++) acc[e] = 0.f;
    for (int i = 0; i < nch; i++) {
        float a = exp2f(Mpart[(tb + i) * 32 + r32] - mm);
        ll += a * Lpart[(tb + i) * 32 + r32];
        const unsigned short* op = Opart + ((size_t)(tb + i) * 32 + r32) * 64 + h0;
        short8 v0 = *(const short8*)op;
        short8 v1 = *(const short8*)(op + 8);
#pragma unroll
        for (int e = 0; e < 8; e++) {
            acc[e]     += a * bf16_to_f32((unsigned short)v0[e]);
            acc[8 + e] += a * bf16_to_f32((unsigned short)v1[e]);
        }
    }
    float inv = 1.f / ll;
    float* dst = out + (size_t)g * 64 + h0;
#pragma unroll
    for (int e = 0; e < 16; e++) dst[e] = acc[e] * inv;
}

extern "C" void kernel_launch(void* const* d_in, const int* in_sizes, int n_in,
                              void* d_out, int out_size, void* d_ws, size_t ws_size,
                              hipStream_t stream) {
    (void)in_sizes; (void)n_in; (void)out_size; (void)ws_size;
    const float* x  = (const float*)d_in[0];
    const float* Wk = (const float*)d_in[1];
    const float* Wq = (const float*)d_in[2];
    const float* Wv = (const float*)d_in[3];
    float* out = (float*)d_out;

    unsigned short* Wb = (unsigned short*)d_ws;              // 192*1024 (swizzled)
    unsigned short* Kb = Wb + 196608;                        // 16384*64
    unsigned short* Qb = Kb + 1048576;                       // pre-scaled by QSCALE
    unsigned short* Vt = Qb + 1048576;                       // (b, 64, t)
    unsigned short* Opart = Vt + 1048576;                    // [4*1088][32][64] bf16
    float* Mpart = (float*)(Opart + (size_t)4 * NTASK * 32 * 64);
    float* Lpart = Mpart + 4 * NTASK * 32;

    hipLaunchKernelGGL(convert_w, dim3(96), dim3(256), 0, stream, Wk, Wq, Wv, Wb);
    hipLaunchKernelGGL(qkv_proj, dim3(512), dim3(256), 0, stream, x, Wb, Kb, Qb, Vt);
    hipLaunchKernelGGL(attn, dim3(4 * NTASK), dim3(64), 0, stream, Qb, Kb, Vt, Opart, Mpart, Lpart);
    hipLaunchKernelGGL(attn_merge, dim3(256), dim3(256), 0, stream, Opart, Mpart, Lpart, out);
}

// Round 11
// 81.815 us; speedup vs baseline: 1.1479x; 1.1384x over previous
//
#include <hip/hip_runtime.h>
#include <hip/hip_bf16.h>

#define D_EMB 1024
#define T_LEN 4096
#define NTASK2 544  // attn supertile-tasks per batch: sum of ceil((st+1)/4), st=0..63

typedef short short8 __attribute__((ext_vector_type(8)));
typedef float f32x4 __attribute__((ext_vector_type(4)));
typedef float f32x16 __attribute__((ext_vector_type(16)));
typedef float float4v __attribute__((ext_vector_type(4)));

__device__ __forceinline__ unsigned short f32_to_bf16(float f) {
    union { float f; unsigned int u; } c; c.f = f;
    unsigned int u = c.u;
    return (unsigned short)((u + 0x7FFFu + ((u >> 16) & 1u)) >> 16);
}
__device__ __forceinline__ float bf16_to_f32(unsigned short v) {
    union { unsigned int u; float f; } c; c.u = ((unsigned int)v) << 16;
    return c.f;
}
__device__ __forceinline__ unsigned cvtpk_bf16(float a, float b) {
    unsigned r;
    asm("v_cvt_pk_bf16_f32 %0, %1, %2" : "=v"(r) : "v"(a), "v"(b));
    return r;
}
// cross-half (lane i <-> i+32) reduce -- known-good __shfl_xor form (R4-R9)
__device__ __forceinline__ float xhalf_max(float x) {
    return fmaxf(x, __shfl_xor(x, 32));
}
__device__ __forceinline__ float xhalf_add(float x) {
    return x + __shfl_xor(x, 32);
}
__device__ __forceinline__ void gl_lds16(const void* g, void* l) {
    __builtin_amdgcn_global_load_lds(
        (const __attribute__((address_space(1))) unsigned int*)(g),
        (__attribute__((address_space(3))) unsigned int*)(l), 16, 0, 0);
}

// scale folded into Q: 1/sqrt(64) * log2(e)  (softmax done in exp2 domain)
#define QSCALE (0.125f * 1.44269504f)

// ---------------- kernel 0: convert W -> bf16, XOR-swizzled within 64-col blocks
__global__ __launch_bounds__(256) void convert_w(const float* __restrict__ Wk,
                                                 const float* __restrict__ Wq,
                                                 const float* __restrict__ Wv,
                                                 unsigned short* __restrict__ Wb) {
    int e = (blockIdx.x * 256 + threadIdx.x) * 8;
    const float* src;
    if (e < 65536) src = Wk + e;
    else if (e < 131072) src = Wq + (e - 65536);
    else src = Wv + (e - 131072);
    float4v a0 = *(const float4v*)src;
    float4v a1 = *(const float4v*)(src + 4);
    short8 r;
    r[0] = (short)f32_to_bf16(a0[0]); r[1] = (short)f32_to_bf16(a0[1]);
    r[2] = (short)f32_to_bf16(a0[2]); r[3] = (short)f32_to_bf16(a0[3]);
    r[4] = (short)f32_to_bf16(a1[0]); r[5] = (short)f32_to_bf16(a1[1]);
    r[6] = (short)f32_to_bf16(a1[2]); r[7] = (short)f32_to_bf16(a1[3]);
    int row = e >> 10;
    int dst = e ^ ((row & 7) << 3);
    *(short8*)(Wb + dst) = r;
}

// ---------------- kernel 1: QKV projection, LDS-staged GEMM + depth-2 x prefetch
__global__ __launch_bounds__(256, 2) void qkv_proj(const float* __restrict__ x,
                                                   const unsigned short* __restrict__ Wb,
                                                   unsigned short* __restrict__ Kb,
                                                   unsigned short* __restrict__ Qb,
                                                   unsigned short* __restrict__ Vt) {
    __shared__ __attribute__((aligned(16))) unsigned short Wsl[2][12288];  // [192][64] bf16

    int tid = threadIdx.x;
    int lane = tid & 63, wave = tid >> 6;
    int lo = lane & 15, hi = lane >> 4;
    int rg = wave >> 1, nh = wave & 1;
    int row0 = blockIdx.x * 32;

    const float* xp = x + (size_t)(row0 + rg * 16 + lo) * D_EMB + hi * 8;

    f32x4 acc[6];
#pragma unroll
    for (int i = 0; i < 6; i++) acc[i] = (f32x4){0.f, 0.f, 0.f, 0.f};

    // x prefetch depth 2: xa = kt, xb = kt+1
    float4v xa0 = *(const float4v*)(xp);
    float4v xa1 = *(const float4v*)(xp + 4);
    float4v xa2 = *(const float4v*)(xp + 32);
    float4v xa3 = *(const float4v*)(xp + 36);
    float4v xb0 = *(const float4v*)(xp + 64);
    float4v xb1 = *(const float4v*)(xp + 68);
    float4v xb2 = *(const float4v*)(xp + 96);
    float4v xb3 = *(const float4v*)(xp + 100);

    // stage W slice 0
#pragma unroll
    for (int j = 0; j < 6; j++) {
        int unit = j * 4 + wave;
        int u = unit * 64 + lane;
        gl_lds16(Wb + (size_t)(u >> 3) * D_EMB + (u & 7) * 8, &Wsl[0][unit * 512]);
    }
    __syncthreads();

    int buf = 0;
    int xorm = (lo & 7) << 4;
    int rowbase = nh * 96 + lo;

    for (int kt = 0; kt < 16; kt++) {
        // issue x loads for kt+2 (clamped)
        int ktn = (kt < 14) ? kt + 2 : 15;
        const float* pn = xp + ktn * 64;
        float4v xc0 = *(const float4v*)(pn);
        float4v xc1 = *(const float4v*)(pn + 4);
        float4v xc2 = *(const float4v*)(pn + 32);
        float4v xc3 = *(const float4v*)(pn + 36);

        // stage W slice kt+1
        if (kt < 15) {
            int k0n = (kt + 1) * 64;
#pragma unroll
            for (int j = 0; j < 6; j++) {
                int unit = j * 4 + wave;
                int u = unit * 64 + lane;
                gl_lds16(Wb + (size_t)(u >> 3) * D_EMB + k0n + (u & 7) * 8,
                         &Wsl[buf ^ 1][unit * 512]);
            }
        }

        // cvt current x -> A fragments
        short8 af[2];
        {
            union { unsigned u[4]; short8 s; } c;
            c.u[0] = cvtpk_bf16(xa0[0], xa0[1]);
            c.u[1] = cvtpk_bf16(xa0[2], xa0[3]);
            c.u[2] = cvtpk_bf16(xa1[0], xa1[1]);
            c.u[3] = cvtpk_bf16(xa1[2], xa1[3]);
            af[0] = c.s;
            c.u[0] = cvtpk_bf16(xa2[0], xa2[1]);
            c.u[1] = cvtpk_bf16(xa2[2], xa2[3]);
            c.u[2] = cvtpk_bf16(xa3[0], xa3[1]);
            c.u[3] = cvtpk_bf16(xa3[2], xa3[3]);
            af[1] = c.s;
        }

        const char* sb = (const char*)&Wsl[buf][0];
#pragma unroll
        for (int i = 0; i < 6; i++) {
            int row = rowbase + i * 16;
#pragma unroll
            for (int ks = 0; ks < 2; ks++) {
                short8 bfrag = *(const short8*)(sb + row * 128 + ((ks * 64 + hi * 16) ^ xorm));
                acc[i] = __builtin_amdgcn_mfma_f32_16x16x32_bf16(af[ks], bfrag, acc[i], 0, 0, 0);
            }
        }
        __syncthreads();
        buf ^= 1;
        xa0 = xb0; xa1 = xb1; xa2 = xb2; xa3 = xb3;
        xb0 = xc0; xb1 = xc1; xb2 = xc2; xb3 = xc3;
    }

    // epilogue
#pragma unroll
    for (int i = 0; i < 6; i++) {
        int n = nh * 6 + i;
#pragma unroll
        for (int r = 0; r < 4; r++) {
            int grow = row0 + rg * 16 + hi * 4 + r;
            float val = acc[i][r];
            if (n < 4) {
                Kb[(size_t)grow * 64 + n * 16 + lo] = f32_to_bf16(val);
            } else if (n < 8) {
                Qb[(size_t)grow * 64 + (n - 4) * 16 + lo] = f32_to_bf16(val * QSCALE);
            } else {
                int bb = grow >> 12;
                Vt[((size_t)bb * 64 + (n - 8) * 16 + lo) * T_LEN + (grow & 4095)] = f32_to_bf16(val);
            }
        }
    }
}

// ---------------- kernel 2: causal flash attention, 1 wave per supertile-task.
// Wave handles TWO adjacent 32-row q-tiles (64-row supertile) against a shared
// chunk of <=8 32-key units: two independent softmax chains interleave in the
// SIMD (intra-wave ILP), K/V loads amortize 2x. Cross-half reduce via
// __shfl_xor (known-good). Branchless diagonal handling (mask -> exp2 -> 0).
__global__ __launch_bounds__(64, 2) void attn(const unsigned short* __restrict__ Qb,
                                              const unsigned short* __restrict__ Kb,
                                              const unsigned short* __restrict__ Vt,
                                              unsigned short* __restrict__ Opart,
                                              float* __restrict__ Mpart,
                                              float* __restrict__ Lpart) {
    int lane = threadIdx.x;
    int q32 = lane & 31;
    int hi = lane >> 5;
    unsigned lin = blockIdx.x;
    int b = lin & 3;
    int s = (int)(((lin >> 3) << 1) | ((lin >> 2) & 1));  // 0..543, heavy first

    // decode (supertile st, chunk c): group k has 4 supertiles, k chunks each
    int k = 16, rem = s;
    while (rem >= 4 * k) { rem -= 4 * k; k--; }
    int ti = rem / k;
    int st = 4 * k - 1 - ti;
    int c = rem - ti * k;

    int u0 = c * 8;
    int u1 = min(u0 + 8, 2 * st + 2);   // 32-key units
    int ta = 2 * st, tb = ta + 1;       // the two 32-row tiles
    int qrowA = 64 * st + q32;
    int qrowB = qrowA + 32;

    size_t base = (size_t)b * T_LEN;

    // Q B-fragments for both tiles
    short8 qfa[4], qfb[4];
    const unsigned short* qpa = Qb + (base + qrowA) * 64 + hi * 8;
    const unsigned short* qpb = Qb + (base + qrowB) * 64 + hi * 8;
#pragma unroll
    for (int d = 0; d < 4; d++) {
        qfa[d] = *(const short8*)(qpa + d * 16);
        qfb[d] = *(const short8*)(qpb + d * 16);
    }

    size_t vbase = ((size_t)b * 64 + q32) * T_LEN;
    f32x16 oA0 = {0.f}, oA1 = {0.f}, oB0 = {0.f}, oB1 = {0.f};
    float mA = -3e38f, lA = 0.f, mB = -3e38f, lB = 0.f;

    for (int u = u0; u < u1; ++u) {
        const unsigned short* kp = Kb + (base + u * 32 + q32) * 64 + hi * 8;
        short8 kc0 = *(const short8*)kp;
        short8 kc1 = *(const short8*)(kp + 16);
        short8 kc2 = *(const short8*)(kp + 32);
        short8 kc3 = *(const short8*)(kp + 48);
        const unsigned short* vp = Vt + vbase + u * 32 + hi * 8;
        short8 vc0 = *(const short8*)vp;
        short8 vc1 = *(const short8*)(vp + 16);
        short8 vc2 = *(const short8*)(vp + 32 * T_LEN);
        short8 vc3 = *(const short8*)(vp + 32 * T_LEN + 16);

        // S^T = K * Q^T for both tiles (independent MFMA chains)
        f32x16 sa = {0.f}, sb = {0.f};
        sa = __builtin_amdgcn_mfma_f32_32x32x16_bf16(kc0, qfa[0], sa, 0, 0, 0);
        sb = __builtin_amdgcn_mfma_f32_32x32x16_bf16(kc0, qfb[0], sb, 0, 0, 0);
        sa = __builtin_amdgcn_mfma_f32_32x32x16_bf16(kc1, qfa[1], sa, 0, 0, 0);
        sb = __builtin_amdgcn_mfma_f32_32x32x16_bf16(kc1, qfb[1], sb, 0, 0, 0);
        sa = __builtin_amdgcn_mfma_f32_32x32x16_bf16(kc2, qfa[2], sa, 0, 0, 0);
        sb = __builtin_amdgcn_mfma_f32_32x32x16_bf16(kc2, qfb[2], sb, 0, 0, 0);
        sa = __builtin_amdgcn_mfma_f32_32x32x16_bf16(kc3, qfa[3], sa, 0, 0, 0);
        sb = __builtin_amdgcn_mfma_f32_32x32x16_bf16(kc3, qfb[3], sb, 0, 0, 0);

        // causal mask: chain A when u >= ta (u==tb -> fully masked, harmless);
        // chain B only at u == tb
        if (u >= ta) {
#pragma unroll
            for (int r = 0; r < 16; ++r) {
                int key = 32 * u + (r & 3) + 8 * (r >> 2) + 4 * hi;
                sa[r] = (key <= qrowA) ? sa[r] : -3e38f;
                if (u == tb) sb[r] = (key <= qrowB) ? sb[r] : -3e38f;
            }
        }

        // row max (both chains) + cross-half
        float a0 = fmaxf(fmaxf(sa[0], sa[1]), sa[2]);
        float a1 = fmaxf(fmaxf(sa[3], sa[4]), sa[5]);
        float a2 = fmaxf(fmaxf(sa[6], sa[7]), sa[8]);
        float a3 = fmaxf(fmaxf(sa[9], sa[10]), sa[11]);
        float a4 = fmaxf(fmaxf(sa[12], sa[13]), sa[14]);
        float mxA = fmaxf(fmaxf(fmaxf(a0, a1), fmaxf(a2, a3)), fmaxf(a4, sa[15]));
        float b0 = fmaxf(fmaxf(sb[0], sb[1]), sb[2]);
        float b1 = fmaxf(fmaxf(sb[3], sb[4]), sb[5]);
        float b2 = fmaxf(fmaxf(sb[6], sb[7]), sb[8]);
        float b3 = fmaxf(fmaxf(sb[9], sb[10]), sb[11]);
        float b4 = fmaxf(fmaxf(sb[12], sb[13]), sb[14]);
        float mxB = fmaxf(fmaxf(fmaxf(b0, b1), fmaxf(b2, b3)), fmaxf(b4, sb[15]));
        mxA = xhalf_max(mxA);
        mxB = xhalf_max(mxB);

        // combined defer-max (THR=8): neutral rescale is exact for the
        // chain that didn't grow (al = exp2(0) = 1)
        float grow = fmaxf(mxA - mA, mxB - mB);
        if (__any(grow > 8.0f)) {
            float mnA = fmaxf(mA, mxA);
            float alA = exp2f(mA - mnA);
            mA = mnA; lA *= alA;
            float mnB = fmaxf(mB, mxB);
            float alB = exp2f(mB - mnB);
            mB = mnB; lB *= alB;
#pragma unroll
            for (int r = 0; r < 16; ++r) {
                oA0[r] *= alA; oA1[r] *= alA;
                oB0[r] *= alB; oB1[r] *= alB;
            }
        }

#pragma unroll
        for (int r = 0; r < 16; ++r) {
            sa[r] = exp2f(sa[r] - mA);
            sb[r] = exp2f(sb[r] - mB);
        }
        float yA = ((sa[0] + sa[8]) + (sa[4] + sa[12])) + ((sa[1] + sa[9]) + (sa[5] + sa[13]))
                 + ((sa[2] + sa[10]) + (sa[6] + sa[14])) + ((sa[3] + sa[11]) + (sa[7] + sa[15]));
        float yB = ((sb[0] + sb[8]) + (sb[4] + sb[12])) + ((sb[1] + sb[9]) + (sb[5] + sb[13]))
                 + ((sb[2] + sb[10]) + (sb[6] + sb[14])) + ((sb[3] + sb[11]) + (sb[7] + sb[15]));
        lA += xhalf_add(yA);
        lB += xhalf_add(yB);

        // pack P -> bf16 PV B-fragments (cvt_pk + permlane32_swap), both chains
        unsigned pa0 = cvtpk_bf16(sa[0],  sa[1]);
        unsigned pa1 = cvtpk_bf16(sa[2],  sa[3]);
        unsigned pa2 = cvtpk_bf16(sa[4],  sa[5]);
        unsigned pa3 = cvtpk_bf16(sa[6],  sa[7]);
        unsigned pa4 = cvtpk_bf16(sa[8],  sa[9]);
        unsigned pa5 = cvtpk_bf16(sa[10], sa[11]);
        unsigned pa6 = cvtpk_bf16(sa[12], sa[13]);
        unsigned pa7 = cvtpk_bf16(sa[14], sa[15]);
        unsigned pb0 = cvtpk_bf16(sb[0],  sb[1]);
        unsigned pb1 = cvtpk_bf16(sb[2],  sb[3]);
        unsigned pb2 = cvtpk_bf16(sb[4],  sb[5]);
        unsigned pb3 = cvtpk_bf16(sb[6],  sb[7]);
        unsigned pb4 = cvtpk_bf16(sb[8],  sb[9]);
        unsigned pb5 = cvtpk_bf16(sb[10], sb[11]);
        unsigned pb6 = cvtpk_bf16(sb[12], sb[13]);
        unsigned pb7 = cvtpk_bf16(sb[14], sb[15]);
        asm("v_permlane32_swap_b32 %0, %1" : "+v"(pa0), "+v"(pa2));
        asm("v_permlane32_swap_b32 %0, %1" : "+v"(pa1), "+v"(pa3));
        asm("v_permlane32_swap_b32 %0, %1" : "+v"(pa4), "+v"(pa6));
        asm("v_permlane32_swap_b32 %0, %1" : "+v"(pa5), "+v"(pa7));
        asm("v_permlane32_swap_b32 %0, %1" : "+v"(pb0), "+v"(pb2));
        asm("v_permlane32_swap_b32 %0, %1" : "+v"(pb1), "+v"(pb3));
        asm("v_permlane32_swap_b32 %0, %1" : "+v"(pb4), "+v"(pb6));
        asm("v_permlane32_swap_b32 %0, %1" : "+v"(pb5), "+v"(pb7));
        union U8 { unsigned u[4]; short8 s; };
        U8 fA0; fA0.u[0] = pa0; fA0.u[1] = pa1; fA0.u[2] = pa2; fA0.u[3] = pa3;
        U8 fA1; fA1.u[0] = pa4; fA1.u[1] = pa5; fA1.u[2] = pa6; fA1.u[3] = pa7;
        U8 fB0; fB0.u[0] = pb0; fB0.u[1] = pb1; fB0.u[2] = pb2; fB0.u[3] = pb3;
        U8 fB1; fB1.u[0] = pb4; fB1.u[1] = pb5; fB1.u[2] = pb6; fB1.u[3] = pb7;

        // O^T += V^T * P^T  (both chains)
        oA0 = __builtin_amdgcn_mfma_f32_32x32x16_bf16(vc0, fA0.s, oA0, 0, 0, 0);
        oB0 = __builtin_amdgcn_mfma_f32_32x32x16_bf16(vc0, fB0.s, oB0, 0, 0, 0);
        oA0 = __builtin_amdgcn_mfma_f32_32x32x16_bf16(vc1, fA1.s, oA0, 0, 0, 0);
        oB0 = __builtin_amdgcn_mfma_f32_32x32x16_bf16(vc1, fB1.s, oB0, 0, 0, 0);
        oA1 = __builtin_amdgcn_mfma_f32_32x32x16_bf16(vc2, fA0.s, oA1, 0, 0, 0);
        oB1 = __builtin_amdgcn_mfma_f32_32x32x16_bf16(vc2, fB0.s, oB1, 0, 0, 0);
        oA1 = __builtin_amdgcn_mfma_f32_32x32x16_bf16(vc3, fA1.s, oA1, 0, 0, 0);
        oB1 = __builtin_amdgcn_mfma_f32_32x32x16_bf16(vc3, fB1.s, oB1, 0, 0, 0);
    }

    // store partials: slotA = (b*544+s)*2, slotB = slotA+1
    int slotA = (b * NTASK2 + s) * 2;
    size_t tbA = ((size_t)slotA * 32 + q32) * 64;
    size_t tbB = ((size_t)(slotA + 1) * 32 + q32) * 64;
#pragma unroll
    for (int hb = 0; hb < 2; hb++) {
#pragma unroll
        for (int g = 0; g < 4; g++) {
            float eA0 = hb ? oA1[4 * g] : oA0[4 * g];
            float eA1 = hb ? oA1[4 * g + 1] : oA0[4 * g + 1];
            float eA2 = hb ? oA1[4 * g + 2] : oA0[4 * g + 2];
            float eA3 = hb ? oA1[4 * g + 3] : oA0[4 * g + 3];
            float eB0 = hb ? oB1[4 * g] : oB0[4 * g];
            float eB1 = hb ? oB1[4 * g + 1] : oB0[4 * g + 1];
            float eB2 = hb ? oB1[4 * g + 2] : oB0[4 * g + 2];
            float eB3 = hb ? oB1[4 * g + 3] : oB0[4 * g + 3];
            int h0 = hb * 32 + g * 8 + hi * 4;
            *reinterpret_cast<uint2*>(Opart + tbA + h0) =
                make_uint2(cvtpk_bf16(eA0, eA1), cvtpk_bf16(eA2, eA3));
            *reinterpret_cast<uint2*>(Opart + tbB + h0) =
                make_uint2(cvtpk_bf16(eB0, eB1), cvtpk_bf16(eB2, eB3));
        }
    }
    if (lane < 32) {
        Mpart[slotA * 32 + q32] = mA;
        Lpart[slotA * 32 + q32] = lA;
        Mpart[(slotA + 1) * 32 + q32] = mB;
        Lpart[(slotA + 1) * 32 + q32] = lB;
    }
}

// ---------------- kernel 3: merge per-chunk partials, divide by l
__global__ __launch_bounds__(256) void attn_merge(const unsigned short* __restrict__ Opart,
                                                  const float* __restrict__ Mpart,
                                                  const float* __restrict__ Lpart,
                                                  float* __restrict__ out) {
    int tid = threadIdx.x;
    int g = blockIdx.x * 64 + (tid >> 2);   // global row
    int h0 = (tid & 3) * 16;
    int b = g >> 12, t = g & 4095;
    int tile32 = t >> 5, r32 = t & 31;
    int st = tile32 >> 1, member = tile32 & 1;
    int k = (st >> 2) + 1;                       // chunks for this supertile
    int sbase = 4 * (136 - ((k * (k + 1)) >> 1));
    int ti = 4 * k - 1 - st;
    int s0 = sbase + ti * k;
    int slot0 = (b * NTASK2 + s0) * 2 + member;  // slots: slot0 + 2*i

    float mm = -3e38f;
    for (int i = 0; i < k; i++) mm = fmaxf(mm, Mpart[(slot0 + 2 * i) * 32 + r32]);
    float ll = 0.f;
    float acc[16];
#pragma unroll
    for (int e = 0; e < 16; e++) acc[e] = 0.f;
    for (int i = 0; i < k; i++) {
        int slot = slot0 + 2 * i;
        float a = exp2f(Mpart[slot * 32 + r32] - mm);
        ll += a * Lpart[slot * 32 + r32];
        const unsigned short* op = Opart + ((size_t)slot * 32 + r32) * 64 + h0;
        short8 v0 = *(const short8*)op;
        short8 v1 = *(const short8*)(op + 8);
#pragma unroll
        for (int e = 0; e < 8; e++) {
            acc[e]     += a * bf16_to_f32((unsigned short)v0[e]);
            acc[8 + e] += a * bf16_to_f32((unsigned short)v1[e]);
        }
    }
    float inv = 1.f / ll;
    float* dst = out + (size_t)g * 64 + h0;
#pragma unroll
    for (int e = 0; e < 16; e++) dst[e] = acc[e] * inv;
}

extern "C" void kernel_launch(void* const* d_in, const int* in_sizes, int n_in,
                              void* d_out, int out_size, void* d_ws, size_t ws_size,
                              hipStream_t stream) {
    (void)in_sizes; (void)n_in; (void)out_size; (void)ws_size;
    const float* x  = (const float*)d_in[0];
    const float* Wk = (const float*)d_in[1];
    const float* Wq = (const float*)d_in[2];
    const float* Wv = (const float*)d_in[3];
    float* out = (float*)d_out;

    unsigned short* Wb = (unsigned short*)d_ws;              // 192*1024 (swizzled)
    unsigned short* Kb = Wb + 196608;                        // 16384*64
    unsigned short* Qb = Kb + 1048576;                       // pre-scaled by QSCALE
    unsigned short* Vt = Qb + 1048576;                       // (b, 64, t)
    unsigned short* Opart = Vt + 1048576;                    // [4*544*2][32][64] bf16
    float* Mpart = (float*)(Opart + (size_t)4 * NTASK2 * 2 * 32 * 64);
    float* Lpart = Mpart + 4 * NTASK2 * 2 * 32;

    hipLaunchKernelGGL(convert_w, dim3(96), dim3(256), 0, stream, Wk, Wq, Wv, Wb);
    hipLaunchKernelGGL(qkv_proj, dim3(512), dim3(256), 0, stream, x, Wb, Kb, Qb, Vt);
    hipLaunchKernelGGL(attn, dim3(4 * NTASK2), dim3(64), 0, stream, Qb, Kb, Vt, Opart, Mpart, Lpart);
    hipLaunchKernelGGL(attn_merge, dim3(256), dim3(256), 0, stream, Opart, Mpart, Lpart, out);
}